// Round 15
// baseline (259.949 us; speedup 1.0000x reference)
//
#include <hip/hip_runtime.h>
#include <math.h>

#define NN 10000
#define EE 320000
#define TILE 32

constexpr float INVS32  = 0.17677669529663687f;   // 1/sqrt(32)
constexpr float INVS160 = 0.07905694150420949f;   // 1/sqrt(160)
constexpr float INVS96  = 0.10206207261596575f;   // 1/sqrt(96)
constexpr float INVS3   = 0.5773502691896258f;    // 1/sqrt(3)
constexpr float INVS2   = 0.7071067811865476f;    // 1/sqrt(2)
constexpr float LN2     = 0.6931471805599453f;

typedef short bf16x8 __attribute__((ext_vector_type(8)));
typedef float f32x4  __attribute__((ext_vector_type(4)));

__device__ __forceinline__ float sspf(float v) {
  return fmaxf(v, 0.f) + __logf(1.f + __expf(-fabsf(v))) - LN2;
}
__device__ __forceinline__ ushort f2bf(float f) {
  union { float f; unsigned u; } v; v.f = f;
  unsigned r = v.u + 0x7FFF + ((v.u >> 16) & 1);   // RNE
  return (ushort)(r >> 16);
}
__device__ __forceinline__ float bf2f(ushort u) {
  return __uint_as_float(((unsigned)u) << 16);
}
__device__ __forceinline__ float bflo(unsigned w) {
  return __uint_as_float(w << 16);
}
__device__ __forceinline__ float bfhi(unsigned w) {
  return __uint_as_float(w & 0xFFFF0000u);
}
__device__ __forceinline__ unsigned pk(float a, float b) {
  return (unsigned)f2bf(a) | ((unsigned)f2bf(b) << 16);
}

// ---------------- sort-by-dst ----------------
__global__ __launch_bounds__(1024) void scan_k(const int* __restrict__ cnt,
                                               int* __restrict__ cursor) {
  __shared__ int s[1024];
  const int t = threadIdx.x;
  int loc[10];
  int sum = 0;
#pragma unroll
  for (int jj = 0; jj < 10; ++jj) {
    int idx = t * 10 + jj;
    int c = (idx < NN) ? cnt[idx] : 0;
    loc[jj] = sum;
    sum += c;
  }
  s[t] = sum;
  __syncthreads();
  for (int d = 1; d < 1024; d <<= 1) {
    int v = (t >= d) ? s[t - d] : 0;
    __syncthreads();
    s[t] += v;
    __syncthreads();
  }
  const int excl = (t > 0) ? s[t - 1] : 0;
#pragma unroll
  for (int jj = 0; jj < 10; ++jj) {
    int idx = t * 10 + jj;
    if (idx < NN) cursor[idx] = excl + loc[jj];
  }
}

// ---------------- weight transforms + fused histogram ----------------
__global__ void prep_t_k(const float* __restrict__ F2, const float* __restrict__ L2,
                         const float* __restrict__ WO0, const float* __restrict__ WO1,
                         const float* __restrict__ WO2,
                         const float* __restrict__ F1, const float* __restrict__ L1,
                         const int* __restrict__ ei, int* __restrict__ cnt,
                         ushort* __restrict__ F2Tb, ushort* __restrict__ L2Tb,
                         float* __restrict__ WO0T, float* __restrict__ WO1T,
                         float* __restrict__ WO2T,
                         ushort* __restrict__ F1Tb, ushort* __restrict__ L1cTb) {
  int i = blockIdx.x * 256 + threadIdx.x;
  if (i < EE) atomicAdd(&cnt[ei[i]], 1);
  if (i < 7168) {                         // F2T/L2T: [c][k] bf16
    int c = i >> 5, k = i & 31;
    float sc = (c < 64)  ? (1.f / 32.f)
             : (c < 128) ? (INVS3 / 32.f)
             : (c < 160) ? (1.f / 32.f)
             : (c < 192) ? (INVS3 / 32.f)
                         : (INVS2 / 32.f);
    F2Tb[i] = f2bf(F2[k * 224 + c] * sc);
    L2Tb[i] = f2bf(L2[k * 224 + c]);
  } else if (i < 7168 + 12288) {          // WO0T [128][96], scale folded
    int j = i - 7168; int k = j / 96, u = j - k * 96;
    WO0T[j] = WO0[u * 128 + k] * INVS96;
  } else if (i < 7168 + 12288 + 6144) {   // WO1T [64][96]
    int j = i - 7168 - 12288; int v = j / 96, u = j - v * 96;
    WO1T[j] = WO1[u * 64 + v] * INVS96;
  } else if (i < 7168 + 12288 + 6144 + 1024) {  // WO2T [32][32]
    int j = i - 7168 - 12288 - 6144; int v = j >> 5, u = j & 31;
    WO2T[j] = WO2[u * 32 + v] * INVS32;
  } else if (i < 26624 + 1024) {          // F1T [32n][32k] bf16, INVS32 folded
    int j = i - 26624; int n = j >> 5, k = j & 31;
    F1Tb[j] = f2bf(F1[k * 32 + n] * INVS32);
  } else if (i < 27648 + 1024) {          // L1cT [32n][32k] bf16, INVS160 folded
    int j = i - 27648; int n = j >> 5, k = j & 31;
    L1cTb[j] = f2bf(L1[(128 + k) * 32 + n] * INVS160);
  }
}

// ---------------- node precompute: 1 wave, 4 nodes, weight-reuse x4 ----------------
__global__ __launch_bounds__(64) void node_prep_k(
    const float* __restrict__ x,
    const float* __restrict__ W0p, const float* __restrict__ b0p,
    const float* __restrict__ W1p,
    const float* __restrict__ W0n, const float* __restrict__ b0n,
    const float* __restrict__ W1n,
    const float* __restrict__ G1, const float* __restrict__ g1b,
    const float* __restrict__ G2, const float* __restrict__ g2b,
    const float* __restrict__ L1,
    const int* __restrict__ ei, int* __restrict__ cursor, int* __restrict__ order,
    ushort* __restrict__ p1b, ushort* __restrict__ x0nb, ushort* __restrict__ x1nb,
    float* __restrict__ Aw, float* __restrict__ Bw)
{
  {  // fused scat
    int gid = blockIdx.x * 64 + threadIdx.x;
#pragma unroll
    for (int r = 0; r < 2; ++r) {
      int e = gid + r * 160000;
      int p = atomicAdd(&cursor[ei[e]], 1);
      order[p] = e;
    }
  }

  const int lane = threadIdx.x;
  const int nb = blockIdx.x * 4;

  __shared__ float sX[4][160];
  __shared__ float sP0[4][64];
  __shared__ float sF0[4][96];
  __shared__ float sH1[4][96];
  __shared__ float sG[4][96];

#pragma unroll
  for (int j = 0; j < 4; ++j) {
    const int n = nb + j;
    sX[j][lane]      = x[n * 160 + lane];
    sX[j][lane + 64] = x[n * 160 + lane + 64];
    if (lane < 32) sX[j][lane + 128] = x[n * 160 + lane + 128];
  }

  {
    float a0 = 0.f, a1 = 0.f, a2 = 0.f, a3 = 0.f;
    for (int i = 0; i < 64; ++i) {
      const float w = W0p[i * 64 + lane];
      a0 = fmaf(sX[0][i], w, a0); a1 = fmaf(sX[1][i], w, a1);
      a2 = fmaf(sX[2][i], w, a2); a3 = fmaf(sX[3][i], w, a3);
    }
    const float b = b0p[lane];
    sP0[0][lane] = a0 * 0.125f + b; sP0[1][lane] = a1 * 0.125f + b;
    sP0[2][lane] = a2 * 0.125f + b; sP0[3][lane] = a3 * 0.125f + b;
#pragma unroll
    for (int j = 0; j < 4; ++j) sF0[j][lane] = sX[j][lane];
  }

  {
    const int o = lane; const int v = o / 3, i_ = o - 3 * v;
    float a0 = 0.f, a1 = 0.f, a2 = 0.f, a3 = 0.f;
    for (int u = 0; u < 32; ++u) {
      const float w = W1p[u * 32 + v];
      a0 = fmaf(sX[0][64 + u * 3 + i_], w, a0);
      a1 = fmaf(sX[1][64 + u * 3 + i_], w, a1);
      a2 = fmaf(sX[2][64 + u * 3 + i_], w, a2);
      a3 = fmaf(sX[3][64 + u * 3 + i_], w, a3);
    }
    p1b[(size_t)(nb + 0) * 96 + o] = f2bf(a0 * INVS32);
    p1b[(size_t)(nb + 1) * 96 + o] = f2bf(a1 * INVS32);
    p1b[(size_t)(nb + 2) * 96 + o] = f2bf(a2 * INVS32);
    p1b[(size_t)(nb + 3) * 96 + o] = f2bf(a3 * INVS32);
  }
  if (lane < 32) {
    const int o = 64 + lane; const int v = o / 3, i_ = o - 3 * v;
    float a0 = 0.f, a1 = 0.f, a2 = 0.f, a3 = 0.f;
    for (int u = 0; u < 32; ++u) {
      const float w = W1p[u * 32 + v];
      a0 = fmaf(sX[0][64 + u * 3 + i_], w, a0);
      a1 = fmaf(sX[1][64 + u * 3 + i_], w, a1);
      a2 = fmaf(sX[2][64 + u * 3 + i_], w, a2);
      a3 = fmaf(sX[3][64 + u * 3 + i_], w, a3);
    }
    p1b[(size_t)(nb + 0) * 96 + o] = f2bf(a0 * INVS32);
    p1b[(size_t)(nb + 1) * 96 + o] = f2bf(a1 * INVS32);
    p1b[(size_t)(nb + 2) * 96 + o] = f2bf(a2 * INVS32);
    p1b[(size_t)(nb + 3) * 96 + o] = f2bf(a3 * INVS32);
  }

  if (lane < 32) {
#pragma unroll
    for (int j = 0; j < 4; ++j) {
      float s2 = 1e-12f;
#pragma unroll
      for (int i = 0; i < 3; ++i) { float t = sX[j][64 + lane * 3 + i]; s2 += t * t; }
      sF0[j][64 + lane] = sqrtf(s2);
    }
  }

  {
    const float b = g1b[lane];
    float a0 = b, a1 = b, a2 = b, a3 = b;
    for (int i = 0; i < 96; ++i) {
      const float w = G1[i * 96 + lane];
      a0 = fmaf(sF0[0][i], w, a0); a1 = fmaf(sF0[1][i], w, a1);
      a2 = fmaf(sF0[2][i], w, a2); a3 = fmaf(sF0[3][i], w, a3);
    }
    sH1[0][lane] = a0 / (1.f + __expf(-a0));
    sH1[1][lane] = a1 / (1.f + __expf(-a1));
    sH1[2][lane] = a2 / (1.f + __expf(-a2));
    sH1[3][lane] = a3 / (1.f + __expf(-a3));
  }
  if (lane < 32) {
    const int o = 64 + lane;
    const float b = g1b[o];
    float a0 = b, a1 = b, a2 = b, a3 = b;
    for (int i = 0; i < 96; ++i) {
      const float w = G1[i * 96 + o];
      a0 = fmaf(sF0[0][i], w, a0); a1 = fmaf(sF0[1][i], w, a1);
      a2 = fmaf(sF0[2][i], w, a2); a3 = fmaf(sF0[3][i], w, a3);
    }
    sH1[0][o] = a0 / (1.f + __expf(-a0));
    sH1[1][o] = a1 / (1.f + __expf(-a1));
    sH1[2][o] = a2 / (1.f + __expf(-a2));
    sH1[3][o] = a3 / (1.f + __expf(-a3));
  }

  {
    const float b = g2b[lane];
    float a0 = b, a1 = b, a2 = b, a3 = b;
    for (int i = 0; i < 96; ++i) {
      const float w = G2[i * 96 + lane];
      a0 = fmaf(sH1[0][i], w, a0); a1 = fmaf(sH1[1][i], w, a1);
      a2 = fmaf(sH1[2][i], w, a2); a3 = fmaf(sH1[3][i], w, a3);
    }
    sG[0][lane] = a0; sG[1][lane] = a1; sG[2][lane] = a2; sG[3][lane] = a3;
  }
  if (lane < 32) {
    const int o = 64 + lane;
    const float b = g2b[o];
    float a0 = b, a1 = b, a2 = b, a3 = b;
    for (int i = 0; i < 96; ++i) {
      const float w = G2[i * 96 + o];
      a0 = fmaf(sH1[0][i], w, a0); a1 = fmaf(sH1[1][i], w, a1);
      a2 = fmaf(sH1[2][i], w, a2); a3 = fmaf(sH1[3][i], w, a3);
    }
    sG[0][o] = a0; sG[1][o] = a1; sG[2][o] = a2; sG[3][o] = a3;
  }

  {
    float a0 = 0.f, a1 = 0.f, a2 = 0.f, a3 = 0.f;
    for (int i = 0; i < 64; ++i) {
      const float w = W0n[i * 64 + lane];
      a0 = fmaf(sG[0][i], w, a0); a1 = fmaf(sG[1][i], w, a1);
      a2 = fmaf(sG[2][i], w, a2); a3 = fmaf(sG[3][i], w, a3);
    }
    const float b = b0n[lane];
    x0nb[(size_t)(nb + 0) * 64 + lane] = f2bf(a0 * 0.125f + b);
    x0nb[(size_t)(nb + 1) * 64 + lane] = f2bf(a1 * 0.125f + b);
    x0nb[(size_t)(nb + 2) * 64 + lane] = f2bf(a2 * 0.125f + b);
    x0nb[(size_t)(nb + 3) * 64 + lane] = f2bf(a3 * 0.125f + b);
  }

  {
    const int o = lane; const int v = o / 3, i_ = o - 3 * v;
    float a0 = 0.f, a1 = 0.f, a2 = 0.f, a3 = 0.f;
    for (int u = 0; u < 32; ++u) {
      const float w = W1n[u * 32 + v];
      a0 = fmaf(sX[0][64 + u * 3 + i_] * sG[0][64 + u], w, a0);
      a1 = fmaf(sX[1][64 + u * 3 + i_] * sG[1][64 + u], w, a1);
      a2 = fmaf(sX[2][64 + u * 3 + i_] * sG[2][64 + u], w, a2);
      a3 = fmaf(sX[3][64 + u * 3 + i_] * sG[3][64 + u], w, a3);
    }
    x1nb[(size_t)(nb + 0) * 96 + o] = f2bf(a0 * INVS32);
    x1nb[(size_t)(nb + 1) * 96 + o] = f2bf(a1 * INVS32);
    x1nb[(size_t)(nb + 2) * 96 + o] = f2bf(a2 * INVS32);
    x1nb[(size_t)(nb + 3) * 96 + o] = f2bf(a3 * INVS32);
  }
  if (lane < 32) {
    const int o = 64 + lane; const int v = o / 3, i_ = o - 3 * v;
    float a0 = 0.f, a1 = 0.f, a2 = 0.f, a3 = 0.f;
    for (int u = 0; u < 32; ++u) {
      const float w = W1n[u * 32 + v];
      a0 = fmaf(sX[0][64 + u * 3 + i_] * sG[0][64 + u], w, a0);
      a1 = fmaf(sX[1][64 + u * 3 + i_] * sG[1][64 + u], w, a1);
      a2 = fmaf(sX[2][64 + u * 3 + i_] * sG[2][64 + u], w, a2);
      a3 = fmaf(sX[3][64 + u * 3 + i_] * sG[3][64 + u], w, a3);
    }
    x1nb[(size_t)(nb + 0) * 96 + o] = f2bf(a0 * INVS32);
    x1nb[(size_t)(nb + 1) * 96 + o] = f2bf(a1 * INVS32);
    x1nb[(size_t)(nb + 2) * 96 + o] = f2bf(a2 * INVS32);
    x1nb[(size_t)(nb + 3) * 96 + o] = f2bf(a3 * INVS32);
  }

  if (lane < 32) {
    float a0 = 0.f, a1 = 0.f, a2 = 0.f, a3 = 0.f;
    float c0 = 0.f, c1 = 0.f, c2 = 0.f, c3 = 0.f;
    for (int i = 0; i < 64; ++i) {
      const float wa = L1[i * 32 + lane];
      const float wb = L1[(64 + i) * 32 + lane];
      a0 = fmaf(sP0[0][i], wa, a0); a1 = fmaf(sP0[1][i], wa, a1);
      a2 = fmaf(sP0[2][i], wa, a2); a3 = fmaf(sP0[3][i], wa, a3);
      c0 = fmaf(sP0[0][i], wb, c0); c1 = fmaf(sP0[1][i], wb, c1);
      c2 = fmaf(sP0[2][i], wb, c2); c3 = fmaf(sP0[3][i], wb, c3);
    }
    Aw[(size_t)(nb + 0) * 32 + lane] = a0 * INVS160;
    Aw[(size_t)(nb + 1) * 32 + lane] = a1 * INVS160;
    Aw[(size_t)(nb + 2) * 32 + lane] = a2 * INVS160;
    Aw[(size_t)(nb + 3) * 32 + lane] = a3 * INVS160;
    Bw[(size_t)(nb + 0) * 32 + lane] = c0 * INVS160;
    Bw[(size_t)(nb + 1) * 32 + lane] = c1 * INVS160;
    Bw[(size_t)(nb + 2) * 32 + lane] = c2 * INVS160;
    Bw[(size_t)(nb + 3) * 32 + lane] = c3 * INVS160;
  }
}

// ---------------- fused per-edge: all-MFMA MLP + vectorized scatter ----------------
__global__ __launch_bounds__(256, 4) void fused_edge_k(
    const float* __restrict__ edge_attr,
    const float* __restrict__ edge_sh,
    const int* __restrict__ ei,
    const ushort* __restrict__ F1Tb, const ushort* __restrict__ L1cTb,
    const ushort* __restrict__ F2Tb, const ushort* __restrict__ L2Tb,
    const ushort* __restrict__ p1b, const float* __restrict__ Aw,
    const float* __restrict__ Bw,
    const ushort* __restrict__ x0nb, const ushort* __restrict__ x1nb,
    const int* __restrict__ order,
    float* __restrict__ o480p)
{
  const int s0  = blockIdx.x * TILE;
  const int tid = threadIdx.x;

  // uMem: sWT (bf16 [224][40], phase C/D) unions with sEAb/sIPb/sAB (phase A/B)
  __shared__ __align__(16) char uMem[224 * 40 * 2];          // 17920 B
  ushort* sWT  = (ushort*)uMem;                  // [c][q] stride 40
  ushort* sEAb = (ushort*)uMem;                  // 32x40 bf16
  ushort* sIPb = (ushort*)(uMem + 2560);         // 32x40 bf16
  float*  sAB  = (float*)(uMem + 5120);          // 32x36 f32

  __shared__ ushort sHF[32][40];
  __shared__ ushort sHL[32][40];
  __shared__ ushort sXS0[32][64];
  __shared__ ushort sXS1p[32 * 136];             // padded triplets [q][u*4+i]
  __shared__ __align__(16) float sSH[32][4];
  __shared__ int    sDst[32];

  const int g = tid >> 3, l = tid & 7;
  const int e   = order[s0 + g];
  const int dst = ei[e];
  const int src = ei[EE + e];
  if (l == 0) sDst[g] = dst;

  // ---- phase A ----
  {
    float4 ea = *(const float4*)(edge_attr + (size_t)e * 32 + l * 4);
    *(unsigned*)&sEAb[g * 40 + l * 4 + 0] = pk(ea.x, ea.y);
    *(unsigned*)&sEAb[g * 40 + l * 4 + 2] = pk(ea.z, ea.w);
  }
  if (l == 1) *(float4*)&sSH[g][0] = *(const float4*)(edge_sh + (size_t)e * 4);
  {
    uint4 v = *(const uint4*)(x0nb + (size_t)src * 64 + l * 8);
    *(uint4*)&sXS0[g][l * 8] = v;
    // x1: load 12 bf16, repack into 4 padded triplets
    const uint2* b2 = (const uint2*)(x1nb + (size_t)src * 96 + l * 12);
    uint2 b0 = b2[0], b1 = b2[1], b2v = b2[2];
    uint2 t0; t0.x = b0.x;                               t0.y = b0.y;
    uint2 t1; t1.x = (b0.y >> 16) | (b1.x << 16);        t1.y = b1.x >> 16;
    uint2 t2; t2.x = b1.y;                               t2.y = b2v.x;
    uint2 t3; t3.x = (b2v.x >> 16) | (b2v.y << 16);      t3.y = b2v.y >> 16;
    ushort* base = &sXS1p[g * 136 + l * 16];
    *(uint2*)&base[0]  = t0;
    *(uint2*)&base[4]  = t1;
    *(uint2*)&base[8]  = t2;
    *(uint2*)&base[12] = t3;
  }
  {
    // ip from bf16 p1 gathers (halved bytes)
    const uint2* pd2 = (const uint2*)(p1b + (size_t)dst * 96 + l * 12);
    const uint2* ps2 = (const uint2*)(p1b + (size_t)src * 96 + l * 12);
    uint2 d0 = pd2[0], d1 = pd2[1], d2 = pd2[2];
    uint2 s0v = ps2[0], s1v = ps2[1], s2v = ps2[2];
    const float dp0 = bflo(d0.x),  dp1 = bfhi(d0.x),  dp2 = bflo(d0.y),  dp3 = bfhi(d0.y);
    const float dp4 = bflo(d1.x),  dp5 = bfhi(d1.x),  dp6 = bflo(d1.y),  dp7 = bfhi(d1.y);
    const float dp8 = bflo(d2.x),  dp9 = bfhi(d2.x),  dp10 = bflo(d2.y), dp11 = bfhi(d2.y);
    const float sp0 = bflo(s0v.x), sp1 = bfhi(s0v.x), sp2 = bflo(s0v.y), sp3 = bfhi(s0v.y);
    const float sp4 = bflo(s1v.x), sp5 = bfhi(s1v.x), sp6 = bflo(s1v.y), sp7 = bfhi(s1v.y);
    const float sp8 = bflo(s2v.x), sp9 = bfhi(s2v.x), sp10 = bflo(s2v.y), sp11 = bfhi(s2v.y);
    const float ip0 = (dp0*sp0 + dp1*sp1 + dp2*sp2) * INVS3;
    const float ip1 = (dp3*sp3 + dp4*sp4 + dp5*sp5) * INVS3;
    const float ip2 = (dp6*sp6 + dp7*sp7 + dp8*sp8) * INVS3;
    const float ip3 = (dp9*sp9 + dp10*sp10 + dp11*sp11) * INVS3;
    *(unsigned*)&sIPb[g * 40 + l * 4 + 0] = pk(ip0, ip1);
    *(unsigned*)&sIPb[g * 40 + l * 4 + 2] = pk(ip2, ip3);
  }
  {
    float4 av = *(const float4*)(Aw + (size_t)dst * 32 + l * 4);
    float4 bv = *(const float4*)(Bw + (size_t)src * 32 + l * 4);
    f32x4 ab;
    ab[0] = av.x + bv.x; ab[1] = av.y + bv.y;
    ab[2] = av.z + bv.z; ab[3] = av.w + bv.w;
    *(f32x4*)&sAB[g * 36 + l * 4] = ab;
  }
  __syncthreads();

  // ---- phase B (MFMA): hf = ea@F1T, hl = ip@L1cT + AB ----
  {
    const int wvi  = tid >> 6;
    const int lane = tid & 63;
    const int r = lane & 15;
    const int h = lane >> 4;
    const int qt = wvi & 1;
    const bool isHL = (wvi >= 2);
    const ushort* aBase = isHL ? sIPb : sEAb;
    const ushort* bW    = isHL ? L1cTb : F1Tb;
    ushort* outB = isHL ? &sHL[0][0] : &sHF[0][0];
    bf16x8 afr = *(const bf16x8*)&aBase[(qt * 16 + r) * 40 + h * 8];
#pragma unroll
    for (int ct = 0; ct < 2; ++ct) {
      const int c = ct * 16 + r;
      bf16x8 bfr = *(const bf16x8*)&bW[c * 32 + h * 8];
      f32x4 z = {0.f, 0.f, 0.f, 0.f};
      f32x4 o = __builtin_amdgcn_mfma_f32_16x16x32_bf16(afr, bfr, z, 0, 0, 0);
#pragma unroll
      for (int i = 0; i < 4; ++i) {
        const int q = qt * 16 + h * 4 + i;
        float v = o[i];
        if (isHL) v += sAB[q * 36 + c];
        outB[q * 40 + c] = f2bf(sspf(v));
      }
    }
  }
  __syncthreads();

  // ---- phase C: MFMA w-GEMMs -> TRANSPOSED sWT[c][q] (uint2 row writes) ----
  {
    const int wv   = tid >> 6;
    const int lane = tid & 63;
    const int r = lane & 15;
    const int h = lane >> 4;
    bf16x8 aF0 = *(const bf16x8*)&sHF[r][h * 8];
    bf16x8 aF1 = *(const bf16x8*)&sHF[16 + r][h * 8];
    bf16x8 aL0 = *(const bf16x8*)&sHL[r][h * 8];
    bf16x8 aL1 = *(const bf16x8*)&sHL[16 + r][h * 8];
    const int ct0 = (wv < 2) ? wv * 4 : 8 + (wv - 2) * 3;
    const int nct = (wv < 2) ? 4 : 3;
    for (int t = 0; t < nct; ++t) {
      const int ct = ct0 + t;
      const int c  = ct * 16 + r;
      bf16x8 bF = *(const bf16x8*)&F2Tb[c * 32 + h * 8];
      bf16x8 bL = *(const bf16x8*)&L2Tb[c * 32 + h * 8];
      f32x4 z = {0.f, 0.f, 0.f, 0.f};
      f32x4 wf0 = __builtin_amdgcn_mfma_f32_16x16x32_bf16(aF0, bF, z, 0, 0, 0);
      f32x4 wl0 = __builtin_amdgcn_mfma_f32_16x16x32_bf16(aL0, bL, z, 0, 0, 0);
      f32x4 wf1 = __builtin_amdgcn_mfma_f32_16x16x32_bf16(aF1, bF, z, 0, 0, 0);
      f32x4 wl1 = __builtin_amdgcn_mfma_f32_16x16x32_bf16(aL1, bL, z, 0, 0, 0);
      uint2 lo; lo.x = pk(wf0[0]*wl0[0], wf0[1]*wl0[1]);
                lo.y = pk(wf0[2]*wl0[2], wf0[3]*wl0[3]);
      uint2 hi; hi.x = pk(wf1[0]*wl1[0], wf1[1]*wl1[1]);
                hi.y = pk(wf1[2]*wl1[2], wf1[3]*wl1[3]);
      *(uint2*)&sWT[c * 40 + h * 4]      = lo;   // q = h*4..h*4+3
      *(uint2*)&sWT[c * 40 + 16 + h * 4] = hi;   // q = 16+h*4..
    }
  }
  __syncthreads();

  // ---- phase D: 128 threads, vectorized w-reads (b128 per 8 edges) ----
  if (tid < 128) {
    const int tl = tid;
    float a0 = 0.f, a1 = 0.f, a2 = 0.f, a3 = 0.f;

    if (tl < 64) {
      for (int p4 = 0; p4 < 4; ++p4) {
        const int q0 = p4 * 8;
        bf16x8 w0v = *(const bf16x8*)&sWT[tl * 40 + q0];
        bf16x8 w1v = *(const bf16x8*)&sWT[(64 + tl) * 40 + q0];
#pragma unroll
        for (int j = 0; j < 8; ++j) {
          const int q = q0 + j;
          const float4 sh = *(const float4*)&sSH[q][0];
          const float x0 = bf2f(sXS0[q][tl]);
          const float w0 = bf2f((ushort)w0v[j]);
          const float w1 = bf2f((ushort)w1v[j]);
          a0 = fmaf(w0 * x0, sh.x, a0);
          const float t = w1 * x0;
          a1 = fmaf(t, sh.y, a1);
          a2 = fmaf(t, sh.z, a2);
          a3 = fmaf(t, sh.w, a3);
          const int d = sDst[q];
          if ((q == TILE - 1) || (sDst[q + 1] != d)) {
            float* dp = o480p + (size_t)d * 480;
            atomicAdd(dp + tl, a0);
            atomicAdd(dp + 128 + tl, a1);
            atomicAdd(dp + 256 + tl, a2);
            atomicAdd(dp + 384 + tl, a3);
            a0 = 0.f; a1 = 0.f; a2 = 0.f; a3 = 0.f;
          }
        }
      }
    } else if (tl < 96) {
      const int c = tl - 64;
      for (int p4 = 0; p4 < 4; ++p4) {
        const int q0 = p4 * 8;
        bf16x8 wbv = *(const bf16x8*)&sWT[(160 + c) * 40 + q0];
        bf16x8 wdv = *(const bf16x8*)&sWT[(128 + c) * 40 + q0];
#pragma unroll
        for (int j = 0; j < 8; ++j) {
          const int q = q0 + j;
          const float4 sh = *(const float4*)&sSH[q][0];
          uint2 t3 = *(const uint2*)&sXS1p[q * 136 + c * 4];
          const float x0v = bflo(t3.x);
          const float x1v = bfhi(t3.x);
          const float x2v = bflo(t3.y);
          const float wb = bf2f((ushort)wbv[j]);
          const float wd = bf2f((ushort)wdv[j]);
          const float d2 = fmaf(x2v, sh.w, fmaf(x1v, sh.z, x0v * sh.y));
          a0 = fmaf(wb, d2, a0);
          const float t = wd * sh.x;
          a1 = fmaf(t, x0v, a1);
          a2 = fmaf(t, x1v, a2);
          a3 = fmaf(t, x2v, a3);
          const int d = sDst[q];
          if ((q == TILE - 1) || (sDst[q + 1] != d)) {
            float* dp = o480p + (size_t)d * 480;
            atomicAdd(dp + tl, a0);
            atomicAdd(dp + 128 + tl, a1);
            atomicAdd(dp + 256 + tl, a2);
            atomicAdd(dp + 384 + tl, a3);
            a0 = 0.f; a1 = 0.f; a2 = 0.f; a3 = 0.f;
          }
        }
      }
    } else {
      const int u = tl - 96;
      for (int p4 = 0; p4 < 4; ++p4) {
        const int q0 = p4 * 8;
        bf16x8 wcv = *(const bf16x8*)&sWT[(192 + u) * 40 + q0];
#pragma unroll
        for (int j = 0; j < 8; ++j) {
          const int q = q0 + j;
          const float4 sh = *(const float4*)&sSH[q][0];
          uint2 t3 = *(const uint2*)&sXS1p[q * 136 + u * 4];
          const float x0v = bflo(t3.x);
          const float x1v = bfhi(t3.x);
          const float x2v = bflo(t3.y);
          const float wc = bf2f((ushort)wcv[j]);
          a0 = fmaf(wc, fmaf(x1v, sh.w, -(x2v * sh.z)), a0);
          a1 = fmaf(wc, fmaf(x2v, sh.y, -(x0v * sh.w)), a1);
          a2 = fmaf(wc, fmaf(x0v, sh.z, -(x1v * sh.y)), a2);
          const int d = sDst[q];
          if ((q == TILE - 1) || (sDst[q + 1] != d)) {
            float* dp = o480p + (size_t)d * 480;
            atomicAdd(dp + tl, a0);
            atomicAdd(dp + 128 + tl, a1);
            atomicAdd(dp + 256 + tl, a2);
            a0 = 0.f; a1 = 0.f; a2 = 0.f;
          }
        }
      }
    }
  }
}

// ---------------- output linears: 1 wave, 4 nodes, acc-major o480p reads ----------------
__global__ __launch_bounds__(64) void out_wo_k(
    const float* __restrict__ o480p,
    const float* __restrict__ WO0T, const float* __restrict__ WO1T,
    const float* __restrict__ WO2T, const float* __restrict__ bO0,
    float* __restrict__ out)
{
  const int lane = threadIdx.x;
  const int nb = blockIdx.x * 4;
  __shared__ float sO[4][480];
#pragma unroll
  for (int j = 0; j < 4; ++j) {
    const float4* src = (const float4*)(o480p + (size_t)(nb + j) * 480);
    for (int idx = lane; idx < 120; idx += 64)
      *(float4*)&sO[j][idx * 4] = src[idx];
  }

  for (int k = lane; k < 416; k += 64) {
    float y0, y1, y2, y3;
    if (k < 128) {
      const float* wr = WO0T + k * 96;
      float a0 = 0.f, a1 = 0.f, a2 = 0.f, a3 = 0.f;
      for (int u = 0; u < 96; ++u) {
        const float w = wr[u];
        a0 = fmaf(w, sO[0][u], a0); a1 = fmaf(w, sO[1][u], a1);
        a2 = fmaf(w, sO[2][u], a2); a3 = fmaf(w, sO[3][u], a3);
      }
      const float b = bO0[k];
      y0 = a0 + b; y1 = a1 + b; y2 = a2 + b; y3 = a3 + b;
    } else if (k < 320) {
      const int kk = k - 128; const int v = kk / 3; const int i = kk - 3 * v;
      const float* wr = WO1T + v * 96;
      const int base = 128 + 128 * i;
      float a0 = 0.f, a1 = 0.f, a2 = 0.f, a3 = 0.f;
      for (int u = 0; u < 96; ++u) {
        const float w = wr[u];
        a0 = fmaf(w, sO[0][base + u], a0);
        a1 = fmaf(w, sO[1][base + u], a1);
        a2 = fmaf(w, sO[2][base + u], a2);
        a3 = fmaf(w, sO[3][base + u], a3);
      }
      y0 = a0; y1 = a1; y2 = a2; y3 = a3;
    } else {
      const int kk = k - 320; const int v = kk / 3; const int i = kk - 3 * v;
      const float* wr = WO2T + v * 32;
      const int base = 96 + 128 * i;
      float a0 = 0.f, a1 = 0.f, a2 = 0.f, a3 = 0.f;
      for (int u = 0; u < 32; ++u) {
        const float w = wr[u];
        a0 = fmaf(w, sO[0][base + u], a0);
        a1 = fmaf(w, sO[1][base + u], a1);
        a2 = fmaf(w, sO[2][base + u], a2);
        a3 = fmaf(w, sO[3][base + u], a3);
      }
      y0 = a0; y1 = a1; y2 = a2; y3 = a3;
    }
    out[(size_t)(nb + 0) * 416 + k] = y0;
    out[(size_t)(nb + 1) * 416 + k] = y1;
    out[(size_t)(nb + 2) * 416 + k] = y2;
    out[(size_t)(nb + 3) * 416 + k] = y3;
  }
}

// ---------------- host ----------------
extern "C" void kernel_launch(void* const* d_in, const int* in_sizes, int n_in,
                              void* d_out, int out_size, void* d_ws, size_t ws_size,
                              hipStream_t stream) {
  const float* x         = (const float*)d_in[0];
  const float* edge_sh   = (const float*)d_in[1];
  const float* edge_attr = (const float*)d_in[2];
  const float* W0p       = (const float*)d_in[3];
  const float* b0p       = (const float*)d_in[4];
  const float* W1p       = (const float*)d_in[5];
  const float* W0n       = (const float*)d_in[6];
  const float* b0n       = (const float*)d_in[7];
  const float* W1n       = (const float*)d_in[8];
  const float* G1        = (const float*)d_in[9];
  const float* g1b       = (const float*)d_in[10];
  const float* G2        = (const float*)d_in[11];
  const float* g2b       = (const float*)d_in[12];
  const float* F1        = (const float*)d_in[13];
  const float* F2        = (const float*)d_in[14];
  const float* L1        = (const float*)d_in[15];
  const float* L2        = (const float*)d_in[16];
  const float* WO0       = (const float*)d_in[17];
  const float* bO0       = (const float*)d_in[18];
  const float* WO1       = (const float*)d_in[19];
  const float* WO2       = (const float*)d_in[20];
  const int*   ei        = (const int*)d_in[21];
  float* out = (float*)d_out;

  ushort* p1b  = (ushort*)d_ws;              // N*96 bf16
  ushort* x0nb = p1b + NN * 96;              // N*64 bf16
  ushort* x1nb = x0nb + NN * 64;             // N*96 bf16
  float*  Aw   = (float*)(x1nb + NN * 96);   // N*32 f32 (256 u16/node -> 4B aligned)
  float*  Bw   = Aw + NN * 32;               // N*32
  float*  o480 = Bw + NN * 32;               // N*480 (acc-major permuted)
  int* cnt    = (int*)(o480 + (size_t)NN * 480);
  int* cursor = cnt    + NN;
  int* order  = cursor + NN;           // E
  uintptr_t p = (uintptr_t)(order + EE);
  p = (p + 15) & ~(uintptr_t)15;
  ushort* F2Tb  = (ushort*)p;          // 224*32 bf16
  ushort* L2Tb  = F2Tb + 224 * 32;
  ushort* F1Tb  = L2Tb + 224 * 32;     // 32*32 bf16
  ushort* L1cTb = F1Tb + 32 * 32;      // 32*32 bf16
  uintptr_t p2 = (uintptr_t)(L1cTb + 32 * 32);
  p2 = (p2 + 15) & ~(uintptr_t)15;
  float* WO0T = (float*)p2;            // 128*96
  float* WO1T = WO0T + 128 * 96;       // 64*96
  float* WO2T = WO1T + 64 * 96;        // 32*32

  hipMemsetAsync(cnt, 0, NN * sizeof(int), stream);
  hipMemsetAsync(o480, 0, (size_t)NN * 480 * sizeof(float), stream);
  prep_t_k<<<(EE + 255) / 256, 256, 0, stream>>>(F2, L2, WO0, WO1, WO2, F1, L1,
                                                 ei, cnt,
                                                 F2Tb, L2Tb, WO0T, WO1T, WO2T,
                                                 F1Tb, L1cTb);
  scan_k<<<1, 1024, 0, stream>>>(cnt, cursor);
  node_prep_k<<<NN / 4, 64, 0, stream>>>(x, W0p, b0p, W1p, W0n, b0n, W1n,
                                         G1, g1b, G2, g2b, L1,
                                         ei, cursor, order,
                                         p1b, x0nb, x1nb, Aw, Bw);
  fused_edge_k<<<EE / TILE, 256, 0, stream>>>(edge_attr, edge_sh, ei,
                                              F1Tb, L1cTb, F2Tb, L2Tb,
                                              p1b, Aw, Bw, x0nb, x1nb,
                                              order, o480);
  out_wo_k<<<NN / 4, 64, 0, stream>>>(o480, WO0T, WO1T, WO2T, bO0, out);
}

// Round 17
// 259.249 us; speedup vs baseline: 1.0027x; 1.0027x over previous
//
#include <hip/hip_runtime.h>
#include <math.h>

#define NN 10000
#define EE 320000
#define TILE 32

constexpr float INVS32  = 0.17677669529663687f;   // 1/sqrt(32)
constexpr float INVS160 = 0.07905694150420949f;   // 1/sqrt(160)
constexpr float INVS96  = 0.10206207261596575f;   // 1/sqrt(96)
constexpr float INVS3   = 0.5773502691896258f;    // 1/sqrt(3)
constexpr float INVS2   = 0.7071067811865476f;    // 1/sqrt(2)
constexpr float LN2     = 0.6931471805599453f;

typedef short bf16x8 __attribute__((ext_vector_type(8)));
typedef float f32x4  __attribute__((ext_vector_type(4)));

__device__ __forceinline__ float sspf(float v) {
  return fmaxf(v, 0.f) + __logf(1.f + __expf(-fabsf(v))) - LN2;
}
__device__ __forceinline__ ushort f2bf(float f) {
  union { float f; unsigned u; } v; v.f = f;
  unsigned r = v.u + 0x7FFF + ((v.u >> 16) & 1);   // RNE
  return (ushort)(r >> 16);
}
__device__ __forceinline__ float bf2f(ushort u) {
  return __uint_as_float(((unsigned)u) << 16);
}
__device__ __forceinline__ float bflo(unsigned w) {
  return __uint_as_float(w << 16);
}
__device__ __forceinline__ float bfhi(unsigned w) {
  return __uint_as_float(w & 0xFFFF0000u);
}
__device__ __forceinline__ unsigned pk(float a, float b) {
  return (unsigned)f2bf(a) | ((unsigned)f2bf(b) << 16);
}

// ---------------- sort-by-dst ----------------
__global__ __launch_bounds__(1024) void scan_k(const int* __restrict__ cnt,
                                               int* __restrict__ cursor) {
  __shared__ int s[1024];
  const int t = threadIdx.x;
  int loc[10];
  int sum = 0;
#pragma unroll
  for (int jj = 0; jj < 10; ++jj) {
    int idx = t * 10 + jj;
    int c = (idx < NN) ? cnt[idx] : 0;
    loc[jj] = sum;
    sum += c;
  }
  s[t] = sum;
  __syncthreads();
  for (int d = 1; d < 1024; d <<= 1) {
    int v = (t >= d) ? s[t - d] : 0;
    __syncthreads();
    s[t] += v;
    __syncthreads();
  }
  const int excl = (t > 0) ? s[t - 1] : 0;
#pragma unroll
  for (int jj = 0; jj < 10; ++jj) {
    int idx = t * 10 + jj;
    if (idx < NN) cursor[idx] = excl + loc[jj];
  }
}

// ---------------- weight transforms + fused histogram ----------------
__global__ void prep_t_k(const float* __restrict__ F2, const float* __restrict__ L2,
                         const float* __restrict__ WO0, const float* __restrict__ WO1,
                         const float* __restrict__ WO2,
                         const float* __restrict__ F1, const float* __restrict__ L1,
                         const int* __restrict__ ei, int* __restrict__ cnt,
                         ushort* __restrict__ F2Tb, ushort* __restrict__ L2Tb,
                         float* __restrict__ WO0T, float* __restrict__ WO1T,
                         float* __restrict__ WO2T,
                         ushort* __restrict__ F1Tb, ushort* __restrict__ L1cTb) {
  int i = blockIdx.x * 256 + threadIdx.x;
  if (i < EE) atomicAdd(&cnt[ei[i]], 1);
  if (i < 7168) {                         // F2T/L2T: [c][k] bf16
    int c = i >> 5, k = i & 31;
    float sc = (c < 64)  ? (1.f / 32.f)
             : (c < 128) ? (INVS3 / 32.f)
             : (c < 160) ? (1.f / 32.f)
             : (c < 192) ? (INVS3 / 32.f)
                         : (INVS2 / 32.f);
    F2Tb[i] = f2bf(F2[k * 224 + c] * sc);
    L2Tb[i] = f2bf(L2[k * 224 + c]);
  } else if (i < 7168 + 12288) {          // WO0T [128][96], scale folded
    int j = i - 7168; int k = j / 96, u = j - k * 96;
    WO0T[j] = WO0[u * 128 + k] * INVS96;
  } else if (i < 7168 + 12288 + 6144) {   // WO1T [64][96]
    int j = i - 7168 - 12288; int v = j / 96, u = j - v * 96;
    WO1T[j] = WO1[u * 64 + v] * INVS96;
  } else if (i < 7168 + 12288 + 6144 + 1024) {  // WO2T [32][32]
    int j = i - 7168 - 12288 - 6144; int v = j >> 5, u = j & 31;
    WO2T[j] = WO2[u * 32 + v] * INVS32;
  } else if (i < 26624 + 1024) {          // F1T [32n][32k] bf16, INVS32 folded
    int j = i - 26624; int n = j >> 5, k = j & 31;
    F1Tb[j] = f2bf(F1[k * 32 + n] * INVS32);
  } else if (i < 27648 + 1024) {          // L1cT [32n][32k] bf16, INVS160 folded
    int j = i - 27648; int n = j >> 5, k = j & 31;
    L1cTb[j] = f2bf(L1[(128 + k) * 32 + n] * INVS160);
  }
}

// ---------------- node precompute: 1 wave, 4 nodes, weight-reuse x4 ----------------
__global__ __launch_bounds__(64) void node_prep_k(
    const float* __restrict__ x,
    const float* __restrict__ W0p, const float* __restrict__ b0p,
    const float* __restrict__ W1p,
    const float* __restrict__ W0n, const float* __restrict__ b0n,
    const float* __restrict__ W1n,
    const float* __restrict__ G1, const float* __restrict__ g1b,
    const float* __restrict__ G2, const float* __restrict__ g2b,
    const float* __restrict__ L1,
    const int* __restrict__ ei, int* __restrict__ cursor, int* __restrict__ order,
    ushort* __restrict__ p1b, ushort* __restrict__ x0nb, ushort* __restrict__ x1nb,
    float* __restrict__ Aw, float* __restrict__ Bw)
{
  {  // fused scat
    int gid = blockIdx.x * 64 + threadIdx.x;
#pragma unroll
    for (int r = 0; r < 2; ++r) {
      int e = gid + r * 160000;
      int p = atomicAdd(&cursor[ei[e]], 1);
      order[p] = e;
    }
  }

  const int lane = threadIdx.x;
  const int nb = blockIdx.x * 4;

  __shared__ float sX[4][160];
  __shared__ float sP0[4][64];
  __shared__ float sF0[4][96];
  __shared__ float sH1[4][96];
  __shared__ float sG[4][96];

#pragma unroll
  for (int j = 0; j < 4; ++j) {
    const int n = nb + j;
    sX[j][lane]      = x[n * 160 + lane];
    sX[j][lane + 64] = x[n * 160 + lane + 64];
    if (lane < 32) sX[j][lane + 128] = x[n * 160 + lane + 128];
  }

  {
    float a0 = 0.f, a1 = 0.f, a2 = 0.f, a3 = 0.f;
    for (int i = 0; i < 64; ++i) {
      const float w = W0p[i * 64 + lane];
      a0 = fmaf(sX[0][i], w, a0); a1 = fmaf(sX[1][i], w, a1);
      a2 = fmaf(sX[2][i], w, a2); a3 = fmaf(sX[3][i], w, a3);
    }
    const float b = b0p[lane];
    sP0[0][lane] = a0 * 0.125f + b; sP0[1][lane] = a1 * 0.125f + b;
    sP0[2][lane] = a2 * 0.125f + b; sP0[3][lane] = a3 * 0.125f + b;
#pragma unroll
    for (int j = 0; j < 4; ++j) sF0[j][lane] = sX[j][lane];
  }

  {
    const int o = lane; const int v = o / 3, i_ = o - 3 * v;
    float a0 = 0.f, a1 = 0.f, a2 = 0.f, a3 = 0.f;
    for (int u = 0; u < 32; ++u) {
      const float w = W1p[u * 32 + v];
      a0 = fmaf(sX[0][64 + u * 3 + i_], w, a0);
      a1 = fmaf(sX[1][64 + u * 3 + i_], w, a1);
      a2 = fmaf(sX[2][64 + u * 3 + i_], w, a2);
      a3 = fmaf(sX[3][64 + u * 3 + i_], w, a3);
    }
    p1b[(size_t)(nb + 0) * 96 + o] = f2bf(a0 * INVS32);
    p1b[(size_t)(nb + 1) * 96 + o] = f2bf(a1 * INVS32);
    p1b[(size_t)(nb + 2) * 96 + o] = f2bf(a2 * INVS32);
    p1b[(size_t)(nb + 3) * 96 + o] = f2bf(a3 * INVS32);
  }
  if (lane < 32) {
    const int o = 64 + lane; const int v = o / 3, i_ = o - 3 * v;
    float a0 = 0.f, a1 = 0.f, a2 = 0.f, a3 = 0.f;
    for (int u = 0; u < 32; ++u) {
      const float w = W1p[u * 32 + v];
      a0 = fmaf(sX[0][64 + u * 3 + i_], w, a0);
      a1 = fmaf(sX[1][64 + u * 3 + i_], w, a1);
      a2 = fmaf(sX[2][64 + u * 3 + i_], w, a2);
      a3 = fmaf(sX[3][64 + u * 3 + i_], w, a3);
    }
    p1b[(size_t)(nb + 0) * 96 + o] = f2bf(a0 * INVS32);
    p1b[(size_t)(nb + 1) * 96 + o] = f2bf(a1 * INVS32);
    p1b[(size_t)(nb + 2) * 96 + o] = f2bf(a2 * INVS32);
    p1b[(size_t)(nb + 3) * 96 + o] = f2bf(a3 * INVS32);
  }

  if (lane < 32) {
#pragma unroll
    for (int j = 0; j < 4; ++j) {
      float s2 = 1e-12f;
#pragma unroll
      for (int i = 0; i < 3; ++i) { float t = sX[j][64 + lane * 3 + i]; s2 += t * t; }
      sF0[j][64 + lane] = sqrtf(s2);
    }
  }

  {
    const float b = g1b[lane];
    float a0 = b, a1 = b, a2 = b, a3 = b;
    for (int i = 0; i < 96; ++i) {
      const float w = G1[i * 96 + lane];
      a0 = fmaf(sF0[0][i], w, a0); a1 = fmaf(sF0[1][i], w, a1);
      a2 = fmaf(sF0[2][i], w, a2); a3 = fmaf(sF0[3][i], w, a3);
    }
    sH1[0][lane] = a0 / (1.f + __expf(-a0));
    sH1[1][lane] = a1 / (1.f + __expf(-a1));
    sH1[2][lane] = a2 / (1.f + __expf(-a2));
    sH1[3][lane] = a3 / (1.f + __expf(-a3));
  }
  if (lane < 32) {
    const int o = 64 + lane;
    const float b = g1b[o];
    float a0 = b, a1 = b, a2 = b, a3 = b;
    for (int i = 0; i < 96; ++i) {
      const float w = G1[i * 96 + o];
      a0 = fmaf(sF0[0][i], w, a0); a1 = fmaf(sF0[1][i], w, a1);
      a2 = fmaf(sF0[2][i], w, a2); a3 = fmaf(sF0[3][i], w, a3);
    }
    sH1[0][o] = a0 / (1.f + __expf(-a0));
    sH1[1][o] = a1 / (1.f + __expf(-a1));
    sH1[2][o] = a2 / (1.f + __expf(-a2));
    sH1[3][o] = a3 / (1.f + __expf(-a3));
  }

  {
    const float b = g2b[lane];
    float a0 = b, a1 = b, a2 = b, a3 = b;
    for (int i = 0; i < 96; ++i) {
      const float w = G2[i * 96 + lane];
      a0 = fmaf(sH1[0][i], w, a0); a1 = fmaf(sH1[1][i], w, a1);
      a2 = fmaf(sH1[2][i], w, a2); a3 = fmaf(sH1[3][i], w, a3);
    }
    sG[0][lane] = a0; sG[1][lane] = a1; sG[2][lane] = a2; sG[3][lane] = a3;
  }
  if (lane < 32) {
    const int o = 64 + lane;
    const float b = g2b[o];
    float a0 = b, a1 = b, a2 = b, a3 = b;
    for (int i = 0; i < 96; ++i) {
      const float w = G2[i * 96 + o];
      a0 = fmaf(sH1[0][i], w, a0); a1 = fmaf(sH1[1][i], w, a1);
      a2 = fmaf(sH1[2][i], w, a2); a3 = fmaf(sH1[3][i], w, a3);
    }
    sG[0][o] = a0; sG[1][o] = a1; sG[2][o] = a2; sG[3][o] = a3;
  }

  {
    float a0 = 0.f, a1 = 0.f, a2 = 0.f, a3 = 0.f;
    for (int i = 0; i < 64; ++i) {
      const float w = W0n[i * 64 + lane];
      a0 = fmaf(sG[0][i], w, a0); a1 = fmaf(sG[1][i], w, a1);
      a2 = fmaf(sG[2][i], w, a2); a3 = fmaf(sG[3][i], w, a3);
    }
    const float b = b0n[lane];
    x0nb[(size_t)(nb + 0) * 64 + lane] = f2bf(a0 * 0.125f + b);
    x0nb[(size_t)(nb + 1) * 64 + lane] = f2bf(a1 * 0.125f + b);
    x0nb[(size_t)(nb + 2) * 64 + lane] = f2bf(a2 * 0.125f + b);
    x0nb[(size_t)(nb + 3) * 64 + lane] = f2bf(a3 * 0.125f + b);
  }

  {
    const int o = lane; const int v = o / 3, i_ = o - 3 * v;
    float a0 = 0.f, a1 = 0.f, a2 = 0.f, a3 = 0.f;
    for (int u = 0; u < 32; ++u) {
      const float w = W1n[u * 32 + v];
      a0 = fmaf(sX[0][64 + u * 3 + i_] * sG[0][64 + u], w, a0);
      a1 = fmaf(sX[1][64 + u * 3 + i_] * sG[1][64 + u], w, a1);
      a2 = fmaf(sX[2][64 + u * 3 + i_] * sG[2][64 + u], w, a2);
      a3 = fmaf(sX[3][64 + u * 3 + i_] * sG[3][64 + u], w, a3);
    }
    x1nb[(size_t)(nb + 0) * 96 + o] = f2bf(a0 * INVS32);
    x1nb[(size_t)(nb + 1) * 96 + o] = f2bf(a1 * INVS32);
    x1nb[(size_t)(nb + 2) * 96 + o] = f2bf(a2 * INVS32);
    x1nb[(size_t)(nb + 3) * 96 + o] = f2bf(a3 * INVS32);
  }
  if (lane < 32) {
    const int o = 64 + lane; const int v = o / 3, i_ = o - 3 * v;
    float a0 = 0.f, a1 = 0.f, a2 = 0.f, a3 = 0.f;
    for (int u = 0; u < 32; ++u) {
      const float w = W1n[u * 32 + v];
      a0 = fmaf(sX[0][64 + u * 3 + i_] * sG[0][64 + u], w, a0);
      a1 = fmaf(sX[1][64 + u * 3 + i_] * sG[1][64 + u], w, a1);
      a2 = fmaf(sX[2][64 + u * 3 + i_] * sG[2][64 + u], w, a2);
      a3 = fmaf(sX[3][64 + u * 3 + i_] * sG[3][64 + u], w, a3);
    }
    x1nb[(size_t)(nb + 0) * 96 + o] = f2bf(a0 * INVS32);
    x1nb[(size_t)(nb + 1) * 96 + o] = f2bf(a1 * INVS32);
    x1nb[(size_t)(nb + 2) * 96 + o] = f2bf(a2 * INVS32);
    x1nb[(size_t)(nb + 3) * 96 + o] = f2bf(a3 * INVS32);
  }

  if (lane < 32) {
    float a0 = 0.f, a1 = 0.f, a2 = 0.f, a3 = 0.f;
    float c0 = 0.f, c1 = 0.f, c2 = 0.f, c3 = 0.f;
    for (int i = 0; i < 64; ++i) {
      const float wa = L1[i * 32 + lane];
      const float wb = L1[(64 + i) * 32 + lane];
      a0 = fmaf(sP0[0][i], wa, a0); a1 = fmaf(sP0[1][i], wa, a1);
      a2 = fmaf(sP0[2][i], wa, a2); a3 = fmaf(sP0[3][i], wa, a3);
      c0 = fmaf(sP0[0][i], wb, c0); c1 = fmaf(sP0[1][i], wb, c1);
      c2 = fmaf(sP0[2][i], wb, c2); c3 = fmaf(sP0[3][i], wb, c3);
    }
    Aw[(size_t)(nb + 0) * 32 + lane] = a0 * INVS160;
    Aw[(size_t)(nb + 1) * 32 + lane] = a1 * INVS160;
    Aw[(size_t)(nb + 2) * 32 + lane] = a2 * INVS160;
    Aw[(size_t)(nb + 3) * 32 + lane] = a3 * INVS160;
    Bw[(size_t)(nb + 0) * 32 + lane] = c0 * INVS160;
    Bw[(size_t)(nb + 1) * 32 + lane] = c1 * INVS160;
    Bw[(size_t)(nb + 2) * 32 + lane] = c2 * INVS160;
    Bw[(size_t)(nb + 3) * 32 + lane] = c3 * INVS160;
  }
}

// ---------------- fused per-edge: all-MFMA MLP + vectorized scatter ----------------
__global__ __launch_bounds__(256, 4) void fused_edge_k(
    const float* __restrict__ edge_attr,
    const float* __restrict__ edge_sh,
    const int* __restrict__ ei,
    const ushort* __restrict__ F1Tb, const ushort* __restrict__ L1cTb,
    const ushort* __restrict__ F2Tb, const ushort* __restrict__ L2Tb,
    const ushort* __restrict__ p1b, const float* __restrict__ Aw,
    const float* __restrict__ Bw,
    const ushort* __restrict__ x0nb, const ushort* __restrict__ x1nb,
    const int* __restrict__ order,
    float* __restrict__ o480p)
{
  const int s0  = blockIdx.x * TILE;
  const int tid = threadIdx.x;

  // uMem: sWT (bf16 [224][40], phase C/D) unions with sEAb/sIPb/sAB (phase A/B)
  __shared__ __align__(16) char uMem[224 * 40 * 2];          // 17920 B
  ushort* sWT  = (ushort*)uMem;                  // [c][q] stride 40
  ushort* sEAb = (ushort*)uMem;                  // 32x40 bf16
  ushort* sIPb = (ushort*)(uMem + 2560);         // 32x40 bf16
  float*  sAB  = (float*)(uMem + 5120);          // 32x36 f32

  __shared__ ushort sHF[32][40];
  __shared__ ushort sHL[32][40];
  __shared__ ushort sXS0[32][64];
  __shared__ ushort sXS1p[32 * 136];             // padded triplets [q][u*4+i]
  __shared__ __align__(16) float sSH[32][4];
  __shared__ int    sDst[32];

  const int g = tid >> 3, l = tid & 7;
  const int e   = order[s0 + g];
  const int dst = ei[e];
  const int src = ei[EE + e];
  if (l == 0) sDst[g] = dst;

  // ---- phase A ----
  {
    float4 ea = *(const float4*)(edge_attr + (size_t)e * 32 + l * 4);
    *(unsigned*)&sEAb[g * 40 + l * 4 + 0] = pk(ea.x, ea.y);
    *(unsigned*)&sEAb[g * 40 + l * 4 + 2] = pk(ea.z, ea.w);
  }
  if (l == 1) *(float4*)&sSH[g][0] = *(const float4*)(edge_sh + (size_t)e * 4);
  {
    uint4 v = *(const uint4*)(x0nb + (size_t)src * 64 + l * 8);
    *(uint4*)&sXS0[g][l * 8] = v;
    // x1: load 12 bf16, repack into 4 padded triplets
    const uint2* b2 = (const uint2*)(x1nb + (size_t)src * 96 + l * 12);
    uint2 b0 = b2[0], b1 = b2[1], b2v = b2[2];
    uint2 t0; t0.x = b0.x;                               t0.y = b0.y;
    uint2 t1; t1.x = (b0.y >> 16) | (b1.x << 16);        t1.y = b1.x >> 16;
    uint2 t2; t2.x = b1.y;                               t2.y = b2v.x;
    uint2 t3; t3.x = (b2v.x >> 16) | (b2v.y << 16);      t3.y = b2v.y >> 16;
    ushort* base = &sXS1p[g * 136 + l * 16];
    *(uint2*)&base[0]  = t0;
    *(uint2*)&base[4]  = t1;
    *(uint2*)&base[8]  = t2;
    *(uint2*)&base[12] = t3;
  }
  {
    // ip from bf16 p1 gathers (halved bytes)
    const uint2* pd2 = (const uint2*)(p1b + (size_t)dst * 96 + l * 12);
    const uint2* ps2 = (const uint2*)(p1b + (size_t)src * 96 + l * 12);
    uint2 d0 = pd2[0], d1 = pd2[1], d2 = pd2[2];
    uint2 s0v = ps2[0], s1v = ps2[1], s2v = ps2[2];
    const float dp0 = bflo(d0.x),  dp1 = bfhi(d0.x),  dp2 = bflo(d0.y),  dp3 = bfhi(d0.y);
    const float dp4 = bflo(d1.x),  dp5 = bfhi(d1.x),  dp6 = bflo(d1.y),  dp7 = bfhi(d1.y);
    const float dp8 = bflo(d2.x),  dp9 = bfhi(d2.x),  dp10 = bflo(d2.y), dp11 = bfhi(d2.y);
    const float sp0 = bflo(s0v.x), sp1 = bfhi(s0v.x), sp2 = bflo(s0v.y), sp3 = bfhi(s0v.y);
    const float sp4 = bflo(s1v.x), sp5 = bfhi(s1v.x), sp6 = bflo(s1v.y), sp7 = bfhi(s1v.y);
    const float sp8 = bflo(s2v.x), sp9 = bfhi(s2v.x), sp10 = bflo(s2v.y), sp11 = bfhi(s2v.y);
    const float ip0 = (dp0*sp0 + dp1*sp1 + dp2*sp2) * INVS3;
    const float ip1 = (dp3*sp3 + dp4*sp4 + dp5*sp5) * INVS3;
    const float ip2 = (dp6*sp6 + dp7*sp7 + dp8*sp8) * INVS3;
    const float ip3 = (dp9*sp9 + dp10*sp10 + dp11*sp11) * INVS3;
    *(unsigned*)&sIPb[g * 40 + l * 4 + 0] = pk(ip0, ip1);
    *(unsigned*)&sIPb[g * 40 + l * 4 + 2] = pk(ip2, ip3);
  }
  {
    float4 av = *(const float4*)(Aw + (size_t)dst * 32 + l * 4);
    float4 bv = *(const float4*)(Bw + (size_t)src * 32 + l * 4);
    f32x4 ab;
    ab[0] = av.x + bv.x; ab[1] = av.y + bv.y;
    ab[2] = av.z + bv.z; ab[3] = av.w + bv.w;
    *(f32x4*)&sAB[g * 36 + l * 4] = ab;
  }
  __syncthreads();

  // ---- phase B (MFMA): hf = ea@F1T, hl = ip@L1cT + AB ----
  {
    const int wvi  = tid >> 6;
    const int lane = tid & 63;
    const int r = lane & 15;
    const int h = lane >> 4;
    const int qt = wvi & 1;
    const bool isHL = (wvi >= 2);
    const ushort* aBase = isHL ? sIPb : sEAb;
    const ushort* bW    = isHL ? L1cTb : F1Tb;
    ushort* outB = isHL ? &sHL[0][0] : &sHF[0][0];
    bf16x8 afr = *(const bf16x8*)&aBase[(qt * 16 + r) * 40 + h * 8];
#pragma unroll
    for (int ct = 0; ct < 2; ++ct) {
      const int c = ct * 16 + r;
      bf16x8 bfr = *(const bf16x8*)&bW[c * 32 + h * 8];
      f32x4 z = {0.f, 0.f, 0.f, 0.f};
      f32x4 o = __builtin_amdgcn_mfma_f32_16x16x32_bf16(afr, bfr, z, 0, 0, 0);
#pragma unroll
      for (int i = 0; i < 4; ++i) {
        const int q = qt * 16 + h * 4 + i;
        float v = o[i];
        if (isHL) v += sAB[q * 36 + c];
        outB[q * 40 + c] = f2bf(sspf(v));
      }
    }
  }
  __syncthreads();

  // ---- phase C: MFMA w-GEMMs -> TRANSPOSED sWT[c][q] (uint2 row writes) ----
  {
    const int wv   = tid >> 6;
    const int lane = tid & 63;
    const int r = lane & 15;
    const int h = lane >> 4;
    bf16x8 aF0 = *(const bf16x8*)&sHF[r][h * 8];
    bf16x8 aF1 = *(const bf16x8*)&sHF[16 + r][h * 8];
    bf16x8 aL0 = *(const bf16x8*)&sHL[r][h * 8];
    bf16x8 aL1 = *(const bf16x8*)&sHL[16 + r][h * 8];
    const int ct0 = (wv < 2) ? wv * 4 : 8 + (wv - 2) * 3;
    const int nct = (wv < 2) ? 4 : 3;
    for (int t = 0; t < nct; ++t) {
      const int ct = ct0 + t;
      const int c  = ct * 16 + r;
      bf16x8 bF = *(const bf16x8*)&F2Tb[c * 32 + h * 8];
      bf16x8 bL = *(const bf16x8*)&L2Tb[c * 32 + h * 8];
      f32x4 z = {0.f, 0.f, 0.f, 0.f};
      f32x4 wf0 = __builtin_amdgcn_mfma_f32_16x16x32_bf16(aF0, bF, z, 0, 0, 0);
      f32x4 wl0 = __builtin_amdgcn_mfma_f32_16x16x32_bf16(aL0, bL, z, 0, 0, 0);
      f32x4 wf1 = __builtin_amdgcn_mfma_f32_16x16x32_bf16(aF1, bF, z, 0, 0, 0);
      f32x4 wl1 = __builtin_amdgcn_mfma_f32_16x16x32_bf16(aL1, bL, z, 0, 0, 0);
      uint2 lo; lo.x = pk(wf0[0]*wl0[0], wf0[1]*wl0[1]);
                lo.y = pk(wf0[2]*wl0[2], wf0[3]*wl0[3]);
      uint2 hi; hi.x = pk(wf1[0]*wl1[0], wf1[1]*wl1[1]);
                hi.y = pk(wf1[2]*wl1[2], wf1[3]*wl1[3]);
      *(uint2*)&sWT[c * 40 + h * 4]      = lo;   // q = h*4..h*4+3
      *(uint2*)&sWT[c * 40 + 16 + h * 4] = hi;   // q = 16+h*4..
    }
  }
  __syncthreads();

  // ---- phase D: 128 threads, vectorized w-reads (b128 per 8 edges) ----
  if (tid < 128) {
    const int tl = tid;
    float a0 = 0.f, a1 = 0.f, a2 = 0.f, a3 = 0.f;

    if (tl < 64) {
      for (int p4 = 0; p4 < 4; ++p4) {
        const int q0 = p4 * 8;
        bf16x8 w0v = *(const bf16x8*)&sWT[tl * 40 + q0];
        bf16x8 w1v = *(const bf16x8*)&sWT[(64 + tl) * 40 + q0];
#pragma unroll
        for (int j = 0; j < 8; ++j) {
          const int q = q0 + j;
          const float4 sh = *(const float4*)&sSH[q][0];
          const float x0 = bf2f(sXS0[q][tl]);
          const float w0 = bf2f((ushort)w0v[j]);
          const float w1 = bf2f((ushort)w1v[j]);
          a0 = fmaf(w0 * x0, sh.x, a0);
          const float t = w1 * x0;
          a1 = fmaf(t, sh.y, a1);
          a2 = fmaf(t, sh.z, a2);
          a3 = fmaf(t, sh.w, a3);
          const int d = sDst[q];
          if ((q == TILE - 1) || (sDst[q + 1] != d)) {
            float* dp = o480p + (size_t)d * 480;
            atomicAdd(dp + tl, a0);
            atomicAdd(dp + 128 + tl, a1);
            atomicAdd(dp + 256 + tl, a2);
            atomicAdd(dp + 384 + tl, a3);
            a0 = 0.f; a1 = 0.f; a2 = 0.f; a3 = 0.f;
          }
        }
      }
    } else if (tl < 96) {
      const int c = tl - 64;
      for (int p4 = 0; p4 < 4; ++p4) {
        const int q0 = p4 * 8;
        bf16x8 wbv = *(const bf16x8*)&sWT[(160 + c) * 40 + q0];
        bf16x8 wdv = *(const bf16x8*)&sWT[(128 + c) * 40 + q0];
#pragma unroll
        for (int j = 0; j < 8; ++j) {
          const int q = q0 + j;
          const float4 sh = *(const float4*)&sSH[q][0];
          uint2 t3 = *(const uint2*)&sXS1p[q * 136 + c * 4];
          const float x0v = bflo(t3.x);
          const float x1v = bfhi(t3.x);
          const float x2v = bflo(t3.y);
          const float wb = bf2f((ushort)wbv[j]);
          const float wd = bf2f((ushort)wdv[j]);
          const float d2 = fmaf(x2v, sh.w, fmaf(x1v, sh.z, x0v * sh.y));
          a0 = fmaf(wb, d2, a0);
          const float t = wd * sh.x;
          a1 = fmaf(t, x0v, a1);
          a2 = fmaf(t, x1v, a2);
          a3 = fmaf(t, x2v, a3);
          const int d = sDst[q];
          if ((q == TILE - 1) || (sDst[q + 1] != d)) {
            float* dp = o480p + (size_t)d * 480;
            atomicAdd(dp + tl, a0);
            atomicAdd(dp + 128 + tl, a1);
            atomicAdd(dp + 256 + tl, a2);
            atomicAdd(dp + 384 + tl, a3);
            a0 = 0.f; a1 = 0.f; a2 = 0.f; a3 = 0.f;
          }
        }
      }
    } else {
      const int u = tl - 96;
      for (int p4 = 0; p4 < 4; ++p4) {
        const int q0 = p4 * 8;
        bf16x8 wcv = *(const bf16x8*)&sWT[(192 + u) * 40 + q0];
#pragma unroll
        for (int j = 0; j < 8; ++j) {
          const int q = q0 + j;
          const float4 sh = *(const float4*)&sSH[q][0];
          uint2 t3 = *(const uint2*)&sXS1p[q * 136 + u * 4];
          const float x0v = bflo(t3.x);
          const float x1v = bfhi(t3.x);
          const float x2v = bflo(t3.y);
          const float wc = bf2f((ushort)wcv[j]);
          a0 = fmaf(wc, fmaf(x1v, sh.w, -(x2v * sh.z)), a0);
          a1 = fmaf(wc, fmaf(x2v, sh.y, -(x0v * sh.w)), a1);
          a2 = fmaf(wc, fmaf(x0v, sh.z, -(x1v * sh.y)), a2);
          const int d = sDst[q];
          if ((q == TILE - 1) || (sDst[q + 1] != d)) {
            float* dp = o480p + (size_t)d * 480;
            atomicAdd(dp + tl, a0);
            atomicAdd(dp + 128 + tl, a1);
            atomicAdd(dp + 256 + tl, a2);
            a0 = 0.f; a1 = 0.f; a2 = 0.f;
          }
        }
      }
    }
  }
}

// ---------------- output linears: 1 wave, 4 nodes, acc-major o480p reads ----------------
__global__ __launch_bounds__(64) void out_wo_k(
    const float* __restrict__ o480p,
    const float* __restrict__ WO0T, const float* __restrict__ WO1T,
    const float* __restrict__ WO2T, const float* __restrict__ bO0,
    float* __restrict__ out)
{
  const int lane = threadIdx.x;
  const int nb = blockIdx.x * 4;
  __shared__ float sO[4][480];
#pragma unroll
  for (int j = 0; j < 4; ++j) {
    const float4* src = (const float4*)(o480p + (size_t)(nb + j) * 480);
    for (int idx = lane; idx < 120; idx += 64)
      *(float4*)&sO[j][idx * 4] = src[idx];
  }

  for (int k = lane; k < 416; k += 64) {
    float y0, y1, y2, y3;
    if (k < 128) {
      const float* wr = WO0T + k * 96;
      float a0 = 0.f, a1 = 0.f, a2 = 0.f, a3 = 0.f;
      for (int u = 0; u < 96; ++u) {
        const float w = wr[u];
        a0 = fmaf(w, sO[0][u], a0); a1 = fmaf(w, sO[1][u], a1);
        a2 = fmaf(w, sO[2][u], a2); a3 = fmaf(w, sO[3][u], a3);
      }
      const float b = bO0[k];
      y0 = a0 + b; y1 = a1 + b; y2 = a2 + b; y3 = a3 + b;
    } else if (k < 320) {
      const int kk = k - 128; const int v = kk / 3; const int i = kk - 3 * v;
      const float* wr = WO1T + v * 96;
      const int base = 128 + 128 * i;
      float a0 = 0.f, a1 = 0.f, a2 = 0.f, a3 = 0.f;
      for (int u = 0; u < 96; ++u) {
        const float w = wr[u];
        a0 = fmaf(w, sO[0][base + u], a0);
        a1 = fmaf(w, sO[1][base + u], a1);
        a2 = fmaf(w, sO[2][base + u], a2);
        a3 = fmaf(w, sO[3][base + u], a3);
      }
      y0 = a0; y1 = a1; y2 = a2; y3 = a3;
    } else {
      const int kk = k - 320; const int v = kk / 3; const int i = kk - 3 * v;
      const float* wr = WO2T + v * 32;
      const int base = 96 + 128 * i;
      float a0 = 0.f, a1 = 0.f, a2 = 0.f, a3 = 0.f;
      for (int u = 0; u < 32; ++u) {
        const float w = wr[u];
        a0 = fmaf(w, sO[0][base + u], a0);
        a1 = fmaf(w, sO[1][base + u], a1);
        a2 = fmaf(w, sO[2][base + u], a2);
        a3 = fmaf(w, sO[3][base + u], a3);
      }
      y0 = a0; y1 = a1; y2 = a2; y3 = a3;
    }
    out[(size_t)(nb + 0) * 416 + k] = y0;
    out[(size_t)(nb + 1) * 416 + k] = y1;
    out[(size_t)(nb + 2) * 416 + k] = y2;
    out[(size_t)(nb + 3) * 416 + k] = y3;
  }
}

// ---------------- host ----------------
extern "C" void kernel_launch(void* const* d_in, const int* in_sizes, int n_in,
                              void* d_out, int out_size, void* d_ws, size_t ws_size,
                              hipStream_t stream) {
  const float* x         = (const float*)d_in[0];
  const float* edge_sh   = (const float*)d_in[1];
  const float* edge_attr = (const float*)d_in[2];
  const float* W0p       = (const float*)d_in[3];
  const float* b0p       = (const float*)d_in[4];
  const float* W1p       = (const float*)d_in[5];
  const float* W0n       = (const float*)d_in[6];
  const float* b0n       = (const float*)d_in[7];
  const float* W1n       = (const float*)d_in[8];
  const float* G1        = (const float*)d_in[9];
  const float* g1b       = (const float*)d_in[10];
  const float* G2        = (const float*)d_in[11];
  const float* g2b       = (const float*)d_in[12];
  const float* F1        = (const float*)d_in[13];
  const float* F2        = (const float*)d_in[14];
  const float* L1        = (const float*)d_in[15];
  const float* L2        = (const float*)d_in[16];
  const float* WO0       = (const float*)d_in[17];
  const float* bO0       = (const float*)d_in[18];
  const float* WO1       = (const float*)d_in[19];
  const float* WO2       = (const float*)d_in[20];
  const int*   ei        = (const int*)d_in[21];
  float* out = (float*)d_out;

  ushort* p1b  = (ushort*)d_ws;              // N*96 bf16
  ushort* x0nb = p1b + NN * 96;              // N*64 bf16
  ushort* x1nb = x0nb + NN * 64;             // N*96 bf16
  float*  Aw   = (float*)(x1nb + NN * 96);   // N*32 f32
  float*  Bw   = Aw + NN * 32;               // N*32
  float*  o480 = Bw + NN * 32;               // N*480 (acc-major permuted)
  int* cnt    = (int*)(o480 + (size_t)NN * 480);
  int* cursor = cnt    + NN;
  int* order  = cursor + NN;           // E
  uintptr_t p = (uintptr_t)(order + EE);
  p = (p + 15) & ~(uintptr_t)15;
  ushort* F2Tb  = (ushort*)p;          // 224*32 bf16
  ushort* L2Tb  = F2Tb + 224 * 32;
  ushort* F1Tb  = L2Tb + 224 * 32;     // 32*32 bf16
  ushort* L1cTb = F1Tb + 32 * 32;      // 32*32 bf16
  uintptr_t p2 = (uintptr_t)(L1cTb + 32 * 32);
  p2 = (p2 + 15) & ~(uintptr_t)15;
  float* WO0T = (float*)p2;            // 128*96
  float* WO1T = WO0T + 128 * 96;       // 64*96
  float* WO2T = WO1T + 64 * 96;        // 32*32

  hipMemsetAsync(cnt, 0, NN * sizeof(int), stream);
  hipMemsetAsync(o480, 0, (size_t)NN * 480 * sizeof(float), stream);
  prep_t_k<<<(EE + 255) / 256, 256, 0, stream>>>(F2, L2, WO0, WO1, WO2, F1, L1,
                                                 ei, cnt,
                                                 F2Tb, L2Tb, WO0T, WO1T, WO2T,
                                                 F1Tb, L1cTb);
  scan_k<<<1, 1024, 0, stream>>>(cnt, cursor);
  node_prep_k<<<NN / 4, 64, 0, stream>>>(x, W0p, b0p, W1p, W0n, b0n, W1n,
                                         G1, g1b, G2, g2b, L1,
                                         ei, cursor, order,
                                         p1b, x0nb, x1nb, Aw, Bw);
  fused_edge_k<<<EE / TILE, 256, 0, stream>>>(edge_attr, edge_sh, ei,
                                              F1Tb, L1cTb, F2Tb, L2Tb,
                                              p1b, Aw, Bw, x0nb, x1nb,
                                              order, o480);
  out_wo_k<<<NN / 4, 64, 0, stream>>>(o480, WO0T, WO1T, WO2T, bO0, out);
}